// Round 16
// baseline (5445.554 us; speedup 1.0000x reference)
//
#include <hip/hip_runtime.h>
#include <hip/hip_bf16.h>

#define TT   1000
#define BB   256
#define HID  256
#define GD   768
#define XD   192
#define NROW (TT*BB)

typedef __attribute__((ext_vector_type(8))) _Float16 half8;
typedef __attribute__((ext_vector_type(4))) float    float4_t;
typedef __attribute__((ext_vector_type(2))) unsigned uint2_t;

#define MFMA16(A,B,C) __builtin_amdgcn_mfma_f32_16x16x32_f16((A),(B),(C),0,0,0)

// AGPRs a0-a127 are asm-owned (wz+wr weights). Pool math (r13/r14/r15 triangulation):
// per-SIMD pool = 512 regs/wave-slot; 8-wave WG = 2 waves/SIMD -> <=256 total/wave.
// r14 (128 arch + 128 agpr) launches and is numerically correct; r13/r15 shapes abort.
#define ACLOB \
  "a0","a1","a2","a3","a4","a5","a6","a7","a8","a9","a10","a11","a12","a13","a14","a15", \
  "a16","a17","a18","a19","a20","a21","a22","a23","a24","a25","a26","a27","a28","a29","a30","a31", \
  "a32","a33","a34","a35","a36","a37","a38","a39","a40","a41","a42","a43","a44","a45","a46","a47", \
  "a48","a49","a50","a51","a52","a53","a54","a55","a56","a57","a58","a59","a60","a61","a62","a63", \
  "a64","a65","a66","a67","a68","a69","a70","a71","a72","a73","a74","a75","a76","a77","a78","a79", \
  "a80","a81","a82","a83","a84","a85","a86","a87","a88","a89","a90","a91","a92","a93","a94","a95", \
  "a96","a97","a98","a99","a100","a101","a102","a103","a104","a105","a106","a107","a108","a109","a110","a111", \
  "a112","a113","a114","a115","a116","a117","a118","a119","a120","a121","a122","a123","a124","a125","a126","a127"

union h8u4 { half8 h; unsigned u[4]; };

__device__ __forceinline__ void gll16(const void* g, void* l) {
  __builtin_amdgcn_global_load_lds((const __attribute__((address_space(1))) void*)g,
                                   (__attribute__((address_space(3))) void*)l, 16, 0, 0);
}

__device__ __forceinline__ unsigned short f2h(float f) {
  _Float16 h = (_Float16)f;                       // RTN-even
  union { _Float16 h; unsigned short u; } c; c.h = h; return c.u;
}
__device__ __forceinline__ uint2_t pk4h(float4_t v) {
  union { _Float16 h[4]; uint2_t u; } c;
  c.h[0] = (_Float16)v.x; c.h[1] = (_Float16)v.y;
  c.h[2] = (_Float16)v.z; c.h[3] = (_Float16)v.w;
  return c.u;
}
__device__ __forceinline__ float4_t h4_to_f4(uint2_t v) {
  union { uint2_t u; _Float16 h[4]; } c; c.u = v;
  float4_t f;
  f.x = (float)c.h[0]; f.y = (float)c.h[1];
  f.z = (float)c.h[2]; f.w = (float)c.h[3];
  return f;
}
__device__ __forceinline__ float sigx(float x) {
  return __builtin_amdgcn_rcpf(1.0f + __builtin_amdgcn_exp2f(-1.4426950408889634f * x));
}
__device__ __forceinline__ float tanhx(float x) {
  return 1.0f - 2.0f * __builtin_amdgcn_rcpf(1.0f + __builtin_amdgcn_exp2f(2.8853900817779268f * x));
}
__device__ __forceinline__ float4_t sig4(float4_t v){ float4_t o; o.x=sigx(v.x); o.y=sigx(v.y); o.z=sigx(v.z); o.w=sigx(v.w); return o; }
__device__ __forceinline__ float4_t tanh4(float4_t v){ float4_t o; o.x=tanhx(v.x); o.y=tanhx(v.y); o.z=tanhx(v.z); o.w=tanhx(v.w); return o; }
__device__ __forceinline__ float gelu1(float v){
  // jax.nn.gelu default = tanh approximation
  float c = v + 0.044715f * v * v * v;
  float e = __builtin_amdgcn_exp2f((0.7978845608028654f * 2.8853900817779268f) * c);
  float th = 1.0f - 2.0f * __builtin_amdgcn_rcpf(1.0f + e);
  return 0.5f * v * (1.0f + th);
}

// ---------------- prep: wiT[n][k] fp16, whF pre-fragmented fp16 ----------------
__global__ void k_prep(const float* __restrict__ wi, const float* __restrict__ wh,
                       unsigned short* __restrict__ wiT, unsigned short* __restrict__ whF)
{
  int tid = blockIdx.x * 256 + threadIdx.x;
  if (tid < GD*XD) {
    int n = tid / XD, k = tid - n*XD;
    wiT[tid] = f2h(wi[(size_t)k*GD + n]);
  }
  int t2 = tid - GD*XD;
  if (t2 >= 0 && t2 < 48*8*64*8) {
    int j = t2 & 7, l = (t2 >> 3) & 63, f = t2 >> 9;
    int mf = f >> 3, kf = f & 7;
    int k = kf*32 + ((l >> 4) << 3) + j;   // A-frag: lane row=l&15 (=ocol), k=(l>>4)*8+j
    int n = (mf << 4) + (l & 15);
    whF[t2] = f2h(wh[(size_t)k*GD + n]);
  }
}

// ---------------- embeddings -> x fp16 [NROW][192] ----------------
__global__ void k_embed(const float* __restrict__ st, const float* __restrict__ ac,
                        const float* __restrict__ rw,
                        const float* __restrict__ Ws, const float* __restrict__ bs,
                        const float* __restrict__ Wa, const float* __restrict__ ba,
                        const float* __restrict__ Wr, const float* __restrict__ br,
                        unsigned short* __restrict__ x)
{
  int lane = threadIdx.x & 63;
  int wid = blockIdx.x * (blockDim.x >> 6) + (threadIdx.x >> 6);
  int nw  = gridDim.x * (blockDim.x >> 6);
  float wsr[64], war[8];
  #pragma unroll
  for (int k = 0; k < 64; ++k) wsr[k] = Ws[k*64 + lane];   // lane j holds Ws[:,j]
  #pragma unroll
  for (int k = 0; k < 8; ++k) war[k] = Wa[k*64 + lane];
  float wrr = Wr[lane];
  float bsv = bs[lane], bav = ba[lane], brv = br[lane];
  for (int row = wid; row < NROW; row += nw) {
    const float4_t* sp = (const float4_t*)(st + (size_t)row*64);
    float a0 = bsv;
    #pragma unroll
    for (int q = 0; q < 16; ++q) {
      float4_t v = sp[q];
      a0 = fmaf(v.x, wsr[4*q+0], a0);
      a0 = fmaf(v.y, wsr[4*q+1], a0);
      a0 = fmaf(v.z, wsr[4*q+2], a0);
      a0 = fmaf(v.w, wsr[4*q+3], a0);
    }
    const float4_t* ap = (const float4_t*)(ac + (size_t)row*8);
    float a1 = bav;
    #pragma unroll
    for (int q = 0; q < 2; ++q) {
      float4_t v = ap[q];
      a1 = fmaf(v.x, war[4*q+0], a1);
      a1 = fmaf(v.y, war[4*q+1], a1);
      a1 = fmaf(v.z, war[4*q+2], a1);
      a1 = fmaf(v.w, war[4*q+3], a1);
    }
    float a2 = fmaf(rw[row], wrr, brv);
    unsigned short* xr = x + (size_t)row*XD;
    xr[lane]       = f2h(gelu1(a0));
    xr[64 + lane]  = f2h(gelu1(a1));
    xr[128 + lane] = f2h(gelu1(a2));
  }
}

// ---------------- gx = x @ wi + bg (fp16), FRAGMENT-LINEAR output ----------------
__global__ __launch_bounds__(512, 2) void k_gx(const unsigned short* __restrict__ x,
                                               const unsigned short* __restrict__ wiT,
                                               const float* __restrict__ bg,
                                               unsigned short* __restrict__ gx)
{
  __shared__ half8 Xs[24*64];   // 24 B-frags (nf*6+kf), lane-linear
  __shared__ half8 As[16*64];   // 16 A-frags per stage phase
  int lane = threadIdx.x & 63;
  int wv   = threadIdx.x >> 6;
  int b    = lane & 15;
  int g8   = (lane >> 4) << 3;
  int row0 = blockIdx.x * 64;
  #pragma unroll
  for (int i = 0; i < 3; ++i) {
    int c = wv*3 + i, nf = c / 6, kf = c - nf*6;
    gll16(x + (size_t)(row0 + nf*16 + b)*XD + kf*32 + g8, &Xs[c*64]);
  }
  int g4 = g8 >> 1;
  float4_t acc[6][4];
  #pragma unroll
  for (int i = 0; i < 6; ++i) {
    float4_t bgv = *(const float4_t*)(bg + (wv + 8*i)*16 + g4);
    #pragma unroll
    for (int nf = 0; nf < 4; ++nf) acc[i][nf] = bgv;   // bias folded into C-init
  }
  half8 xb[4];
  for (int kf = 0; kf < 6; ++kf) {
    #pragma unroll
    for (int p = 0; p < 3; ++p) {
      __syncthreads();                      // prev phase's reads done
      #pragma unroll
      for (int i2 = 0; i2 < 2; ++i2) {
        int q = wv*2 + i2;
        gll16(wiT + (size_t)((p*16 + q)*16 + b)*XD + kf*32 + g8, &As[q*64]);
      }
      __syncthreads();                      // stage complete (drains vmcnt)
      if (p == 0) {
        #pragma unroll
        for (int nf = 0; nf < 4; ++nf) xb[nf] = Xs[(nf*6 + kf)*64 + lane];
      }
      half8 af0 = As[wv*64 + lane];
      half8 af1 = As[(wv+8)*64 + lane];
      #pragma unroll
      for (int nf = 0; nf < 4; ++nf) {
        acc[2*p  ][nf] = MFMA16(af0, xb[nf], acc[2*p  ][nf]);
        acc[2*p+1][nf] = MFMA16(af1, xb[nf], acc[2*p+1][nf]);
      }
    }
  }
  char* gxc = (char*)gx;
  #pragma unroll
  for (int i = 0; i < 6; ++i) {
    #pragma unroll
    for (int nf = 0; nf < 4; ++nf) {
      size_t idx = (((size_t)blockIdx.x*48 + (wv + 8*i))*4 + nf)*512 + lane*8;
      *(uint2_t*)(gxc + idx) = pk4h(acc[i][nf]);
    }
  }
}

// ---------------- GRU recurrence v10: r14 machinery + wa-FIRST vmcnt ordering ----------------
// r14 (proven correct) had one defect: wa loads issued AFTER the prefetch glls,
// so phase-2's wa wait (in-order vmcnt) drained the prefetch every step. Fix:
// queue order per step = [wa x16][gll x3][out-store] -> the wa wait resolves at
// vmcnt(3..7), glls stay in flight across the whole step.
__global__
__attribute__((amdgpu_flat_work_group_size(512, 512), amdgpu_waves_per_eu(2, 2)))
void k_gru(const unsigned short* __restrict__ gx,
           const unsigned short* __restrict__ whF,
           float* __restrict__ out)
{
  __shared__ char smem[98304];     // STATIC (1 WG/CU): h 8448 + rh 8448 + 2x24576 slabs
  char* h_lds  = smem;             // [16][264] fp16: row stride 528 B
  char* rh_lds = smem + 8448;
  char* gxb    = smem + 16896;     // 2 x 24576 B frag-linear slab
  const int tid  = threadIdx.x;
  const int lane = tid & 63;
  const int wv   = tid >> 6;
  const int wg   = blockIdx.x;
  const int b    = lane & 15;
  const int g    = lane >> 4;
  const int kr4  = g << 2;
  const int g16  = g << 4;

  // ---- pin wz+wr into fixed AGPRs a0-a127 (once) ----
#define PIN(FK, S0,S1,S2,S3) do { h8u4 _c; \
    _c.h = *(const half8*)(whF + ((size_t)((FK)*64 + lane) << 3)); \
    asm volatile("v_accvgpr_write_b32 a" S0 ", %0\n\t" \
                 "v_accvgpr_write_b32 a" S1 ", %1\n\t" \
                 "v_accvgpr_write_b32 a" S2 ", %2\n\t" \
                 "v_accvgpr_write_b32 a" S3 ", %3" \
                 :: "v"(_c.u[0]), "v"(_c.u[1]), "v"(_c.u[2]), "v"(_c.u[3]) : ACLOB); } while(0)
  // wz0 -> a0..a31   (FK = 16*wv + kf)
  PIN(16*wv+0,  "0","1","2","3");     PIN(16*wv+1,  "4","5","6","7");
  PIN(16*wv+2,  "8","9","10","11");   PIN(16*wv+3,  "12","13","14","15");
  PIN(16*wv+4,  "16","17","18","19"); PIN(16*wv+5,  "20","21","22","23");
  PIN(16*wv+6,  "24","25","26","27"); PIN(16*wv+7,  "28","29","30","31");
  // wz1 -> a32..a63  (FK = 16*wv + 8 + kf)
  PIN(16*wv+8,  "32","33","34","35"); PIN(16*wv+9,  "36","37","38","39");
  PIN(16*wv+10, "40","41","42","43"); PIN(16*wv+11, "44","45","46","47");
  PIN(16*wv+12, "48","49","50","51"); PIN(16*wv+13, "52","53","54","55");
  PIN(16*wv+14, "56","57","58","59"); PIN(16*wv+15, "60","61","62","63");
  // wr0 -> a64..a95  (FK = 128 + 16*wv + kf)
  PIN(128+16*wv+0, "64","65","66","67");   PIN(128+16*wv+1, "68","69","70","71");
  PIN(128+16*wv+2, "72","73","74","75");   PIN(128+16*wv+3, "76","77","78","79");
  PIN(128+16*wv+4, "80","81","82","83");   PIN(128+16*wv+5, "84","85","86","87");
  PIN(128+16*wv+6, "88","89","90","91");   PIN(128+16*wv+7, "92","93","94","95");
  // wr1 -> a96..a127 (FK = 136 + 16*wv + kf)
  PIN(136+16*wv+0, "96","97","98","99");    PIN(136+16*wv+1, "100","101","102","103");
  PIN(136+16*wv+2, "104","105","106","107");PIN(136+16*wv+3, "108","109","110","111");
  PIN(136+16*wv+4, "112","113","114","115");PIN(136+16*wv+5, "116","117","118","119");
  PIN(136+16*wv+6, "120","121","122","123");PIN(136+16*wv+7, "124","125","126","127");
#undef PIN

  for (int i = tid; i < 2112; i += 512) ((unsigned*)h_lds)[i] = 0u;   // h0 = 0 (8448 B)

  // slab staging: frag-linear (see k_gx). Dest D = i*8192 + tid*16.
  const int nf   = wg & 3;
  const int bsel = wg >> 2;
  int soff[3], dch[3];
  #pragma unroll
  for (int i = 0; i < 3; ++i) {
    int c = i*16 + (tid >> 5);
    int r = (tid & 31) << 4;
    soff[i] = nf*512 + c*2048 + r;
    dch[i]  = i*8192 + tid*16;
  }
  const char* gxc = (const char*)gx;
  #pragma unroll
  for (int i = 0; i < 3; ++i)
    gll16(gxc + (size_t)bsel*98304 + soff[i], gxb + dch[i]);
  __syncthreads();   // full drain: t=0 slab ready, h zeroed, pins done

  float4_t hf0 = {0.f, 0.f, 0.f, 0.f}, hf1 = hf0;   // fp32 h for owned cols
  const char* hb_base = h_lds + b*528;
  const char* rb_base = rh_lds + b*528;
  const int off_h0 = (wv*32 + kr4) << 1;
  const int off_h1 = off_h0 + 32;
  const int lz0 = ( 2*wv    )*512 + lane*8;
  const int lz1 = ( 2*wv + 1)*512 + lane*8;
  const int lr0 = (16 + 2*wv)*512 + lane*8;
  const int lr1 = (17 + 2*wv)*512 + lane*8;
  const int la0 = (32 + 2*wv)*512 + lane*8;
  const int la1 = (33 + 2*wv)*512 + lane*8;
  const unsigned short* wap = whF;   // wa stream base; redefined per-iter (blocks LICM)

  for (int t = 0; t < TT; ++t) {
    // TOP barrier: vmcnt(2) -> glls (issued last iter, before the out-stores... 
    // queue = [gll x3][store x2]) done; stores may stay in flight
    asm volatile("s_waitcnt vmcnt(2) lgkmcnt(0)" ::: "memory", ACLOB);
    __builtin_amdgcn_s_barrier();
    asm volatile("" ::: "memory");

    // wa stream FIRST: vmcnt queue becomes [wa x16][gll x3]; phase-2's wa wait
    // leaves the glls outstanding. Pointer redef blocks LICM; sched_barrier
    // pins the loads here (cannot sink below or let glls hoist above).
    asm volatile("" : "+s"(wap));
    half8 wa00 = *(const half8*)(wap + ((size_t)((256+16*wv+0)*64 + lane) << 3));
    half8 wa01 = *(const half8*)(wap + ((size_t)((256+16*wv+1)*64 + lane) << 3));
    half8 wa02 = *(const half8*)(wap + ((size_t)((256+16*wv+2)*64 + lane) << 3));
    half8 wa03 = *(const half8*)(wap + ((size_t)((256+16*wv+3)*64 + lane) << 3));
    half8 wa04 = *(const half8*)(wap + ((size_t)((256+16*wv+4)*64 + lane) << 3));
    half8 wa05 = *(const half8*)(wap + ((size_t)((256+16*wv+5)*64 + lane) << 3));
    half8 wa06 = *(const half8*)(wap + ((size_t)((256+16*wv+6)*64 + lane) << 3));
    half8 wa07 = *(const half8*)(wap + ((size_t)((256+16*wv+7)*64 + lane) << 3));
    half8 wa10 = *(const half8*)(wap + ((size_t)((264+16*wv+0)*64 + lane) << 3));
    half8 wa11 = *(const half8*)(wap + ((size_t)((264+16*wv+1)*64 + lane) << 3));
    half8 wa12 = *(const half8*)(wap + ((size_t)((264+16*wv+2)*64 + lane) << 3));
    half8 wa13 = *(const half8*)(wap + ((size_t)((264+16*wv+3)*64 + lane) << 3));
    half8 wa14 = *(const half8*)(wap + ((size_t)((264+16*wv+4)*64 + lane) << 3));
    half8 wa15 = *(const half8*)(wap + ((size_t)((264+16*wv+5)*64 + lane) << 3));
    half8 wa16 = *(const half8*)(wap + ((size_t)((264+16*wv+6)*64 + lane) << 3));
    half8 wa17 = *(const half8*)(wap + ((size_t)((264+16*wv+7)*64 + lane) << 3));
    __builtin_amdgcn_sched_barrier(0);

    if (t + 1 < TT) {   // prefetch next slab; stays in flight across the whole step
      const char* slab = gxc + ((size_t)(t+1)*4 + bsel)*98304;
      char* dstb = gxb + 24576*((t+1) & 1);
      #pragma unroll
      for (int i = 0; i < 3; ++i) gll16(slab + soff[i], dstb + dch[i]);
    }
    __builtin_amdgcn_sched_barrier(0);

    const char* cur = gxb + 24576*(t & 1);
    // ---- phase 1: zr^T = sigmoid(gx_zr + wh_zr^T @ h^T) ----
    float4_t az0 = h4_to_f4(*(const uint2_t*)(cur + lz0));
    float4_t az1 = h4_to_f4(*(const uint2_t*)(cur + lz1));
    float4_t ar0 = h4_to_f4(*(const uint2_t*)(cur + lr0));
    float4_t ar1 = h4_to_f4(*(const uint2_t*)(cur + lr1));
    half8 hb0 = *(const half8*)(hb_base + 0*64 + g16);
    half8 hb1 = *(const half8*)(hb_base + 1*64 + g16);
    half8 hb2 = *(const half8*)(hb_base + 2*64 + g16);
    half8 hb3 = *(const half8*)(hb_base + 3*64 + g16);
    half8 hb4 = *(const half8*)(hb_base + 4*64 + g16);
    half8 hb5 = *(const half8*)(hb_base + 5*64 + g16);
    half8 hb6 = *(const half8*)(hb_base + 6*64 + g16);
    half8 hb7 = *(const half8*)(hb_base + 7*64 + g16);
    asm volatile(
      "s_nop 1\n\t"
      "v_mfma_f32_16x16x32_f16 %0, a[0:3], %4, %0\n\t"
      "v_mfma_f32_16x16x32_f16 %1, a[32:35], %4, %1\n\t"
      "v_mfma_f32_16x16x32_f16 %2, a[64:67], %4, %2\n\t"
      "v_mfma_f32_16x16x32_f16 %3, a[96:99], %4, %3\n\t"
      "v_mfma_f32_16x16x32_f16 %0, a[4:7], %5, %0\n\t"
      "v_mfma_f32_16x16x32_f16 %1, a[36:39], %5, %1\n\t"
      "v_mfma_f32_16x16x32_f16 %2, a[68:71], %5, %2\n\t"
      "v_mfma_f32_16x16x32_f16 %3, a[100:103], %5, %3\n\t"
      "v_mfma_f32_16x16x32_f16 %0, a[8:11], %6, %0\n\t"
      "v_mfma_f32_16x16x32_f16 %1, a[40:43], %6, %1\n\t"
      "v_mfma_f32_16x16x32_f16 %2, a[72:75], %6, %2\n\t"
      "v_mfma_f32_16x16x32_f16 %3, a[104:107], %6, %3\n\t"
      "v_mfma_f32_16x16x32_f16 %0, a[12:15], %7, %0\n\t"
      "v_mfma_f32_16x16x32_f16 %1, a[44:47], %7, %1\n\t"
      "v_mfma_f32_16x16x32_f16 %2, a[76:79], %7, %2\n\t"
      "v_mfma_f32_16x16x32_f16 %3, a[108:111], %7, %3\n\t"
      "v_mfma_f32_16x16x32_f16 %0, a[16:19], %8, %0\n\t"
      "v_mfma_f32_16x16x32_f16 %1, a[48:51], %8, %1\n\t"
      "v_mfma_f32_16x16x32_f16 %2, a[80:83], %8, %2\n\t"
      "v_mfma_f32_16x16x32_f16 %3, a[112:115], %8, %3\n\t"
      "v_mfma_f32_16x16x32_f16 %0, a[20:23], %9, %0\n\t"
      "v_mfma_f32_16x16x32_f16 %1, a[52:55], %9, %1\n\t"
      "v_mfma_f32_16x16x32_f16 %2, a[84:87], %9, %2\n\t"
      "v_mfma_f32_16x16x32_f16 %3, a[116:119], %9, %3\n\t"
      "v_mfma_f32_16x16x32_f16 %0, a[24:27], %10, %0\n\t"
      "v_mfma_f32_16x16x32_f16 %1, a[56:59], %10, %1\n\t"
      "v_mfma_f32_16x16x32_f16 %2, a[88:91], %10, %2\n\t"
      "v_mfma_f32_16x16x32_f16 %3, a[120:123], %10, %3\n\t"
      "v_mfma_f32_16x16x32_f16 %0, a[28:31], %11, %0\n\t"
      "v_mfma_f32_16x16x32_f16 %1, a[60:63], %11, %1\n\t"
      "v_mfma_f32_16x16x32_f16 %2, a[92:95], %11, %2\n\t"
      "v_mfma_f32_16x16x32_f16 %3, a[124:127], %11, %3\n\t"
      "s_nop 7\n\t"
      "s_nop 7"
      : "+v"(az0), "+v"(az1), "+v"(ar0), "+v"(ar1)
      : "v"(hb0), "v"(hb1), "v"(hb2), "v"(hb3),
        "v"(hb4), "v"(hb5), "v"(hb6), "v"(hb7)
      : ACLOB);
    float4_t z0 = sig4(az0), z1 = sig4(az1);
    float4_t rh0 = sig4(ar0) * hf0, rh1 = sig4(ar1) * hf1;   // r*h, all in-lane
    *(uint2_t*)(rh_lds + b*528 + off_h0) = pk4h(rh0);
    *(uint2_t*)(rh_lds + b*528 + off_h1) = pk4h(rh1);
    // MID barrier: LDS-only wait, prefetch glls + (already-arrived) wa stay queued
    asm volatile("s_waitcnt lgkmcnt(0)" ::: "memory", ACLOB);
    __builtin_amdgcn_s_barrier();
    asm volatile("" ::: "memory");
    // ---- phase 2: a^T = tanh(gx_a + wh_a^T @ (r*h)^T) ----
    float4_t aa0 = h4_to_f4(*(const uint2_t*)(cur + la0));
    float4_t aa1 = h4_to_f4(*(const uint2_t*)(cur + la1));
    half8 rb0 = *(const half8*)(rb_base + 0*64 + g16);
    half8 rb1 = *(const half8*)(rb_base + 1*64 + g16);
    half8 rb2 = *(const half8*)(rb_base + 2*64 + g16);
    half8 rb3 = *(const half8*)(rb_base + 3*64 + g16);
    asm volatile(
      "s_nop 2\n\t"
      "v_mfma_f32_16x16x32_f16 %0, %2, %10, %0\n\t"
      "v_mfma_f32_16x16x32_f16 %1, %6, %10, %1\n\t"
      "v_mfma_f32_16x16x32_f16 %0, %3, %11, %0\n\t"
      "v_mfma_f32_16x16x32_f16 %1, %7, %11, %1\n\t"
      "v_mfma_f32_16x16x32_f16 %0, %4, %12, %0\n\t"
      "v_mfma_f32_16x16x32_f16 %1, %8, %12, %1\n\t"
      "v_mfma_f32_16x16x32_f16 %0, %5, %13, %0\n\t"
      "v_mfma_f32_16x16x32_f16 %1, %9, %13, %1"
      : "+v"(aa0), "+v"(aa1)
      : "v"(wa00), "v"(wa01), "v"(wa02), "v"(wa03),
        "v"(wa10), "v"(wa11), "v"(wa12), "v"(wa13),
        "v"(rb0), "v"(rb1), "v"(rb2), "v"(rb3)
      : ACLOB);
    half8 rb4 = *(const half8*)(rb_base + 4*64 + g16);
    half8 rb5 = *(const half8*)(rb_base + 5*64 + g16);
    half8 rb6 = *(const half8*)(rb_base + 6*64 + g16);
    half8 rb7 = *(const half8*)(rb_base + 7*64 + g16);
    asm volatile(
      "s_nop 2\n\t"
      "v_mfma_f32_16x16x32_f16 %0, %2, %10, %0\n\t"
      "v_mfma_f32_16x16x32_f16 %1, %6, %10, %1\n\t"
      "v_mfma_f32_16x16x32_f16 %0, %3, %11, %0\n\t"
      "v_mfma_f32_16x16x32_f16 %1, %7, %11, %1\n\t"
      "v_mfma_f32_16x16x32_f16 %0, %4, %12, %0\n\t"
      "v_mfma_f32_16x16x32_f16 %1, %8, %12, %1\n\t"
      "v_mfma_f32_16x16x32_f16 %0, %5, %13, %0\n\t"
      "v_mfma_f32_16x16x32_f16 %1, %9, %13, %1\n\t"
      "s_nop 7\n\t"
      "s_nop 7"
      : "+v"(aa0), "+v"(aa1)
      : "v"(wa04), "v"(wa05), "v"(wa06), "v"(wa07),
        "v"(wa14), "v"(wa15), "v"(wa16), "v"(wa17),
        "v"(rb4), "v"(rb5), "v"(rb6), "v"(rb7)
      : ACLOB);
    float4_t a0 = tanh4(aa0), a1 = tanh4(aa1);
    float4_t hn0 = hf0 + z0 * (a0 - hf0);   // (1-z)h + z*a
    float4_t hn1 = hf1 + z1 * (a1 - hf1);
    hf0 = hn0; hf1 = hn1;
    *(uint2_t*)(h_lds + b*528 + off_h0) = pk4h(hn0);
    *(uint2_t*)(h_lds + b*528 + off_h1) = pk4h(hn1);
    float* op = out + (((size_t)t*BB + wg*16 + b) << 8) + wv*32 + kr4;
    *(float4_t*)op = hn0;
    *(float4_t*)(op + 16) = hn1;
  }
}

extern "C" void kernel_launch(void* const* d_in, const int* in_sizes, int n_in,
                              void* d_out, int out_size, void* d_ws, size_t ws_size,
                              hipStream_t stream) {
  (void)in_sizes; (void)n_in; (void)out_size; (void)ws_size;
  const float* states  = (const float*)d_in[0];
  const float* actions = (const float*)d_in[1];
  const float* rewards = (const float*)d_in[2];
  const float* Ws = (const float*)d_in[3];
  const float* bs = (const float*)d_in[4];
  const float* Wa = (const float*)d_in[5];
  const float* ba = (const float*)d_in[6];
  const float* Wr = (const float*)d_in[7];
  const float* br = (const float*)d_in[8];
  const float* wi = (const float*)d_in[9];
  const float* wh = (const float*)d_in[10];
  const float* bg = (const float*)d_in[11];
  char* wsb = (char*)d_ws;
  // workspace layout (requires ~492.3 MB):
  unsigned short* gx  = (unsigned short*)(wsb);                   // 393,216,000 B
  unsigned short* x   = (unsigned short*)(wsb + 393216000LL);     //  98,304,000 B
  unsigned short* wiT = (unsigned short*)(wsb + 491520000LL);     //     294,912 B
  unsigned short* whF = (unsigned short*)(wsb + 491814912LL);     //     393,216 B
  k_prep <<<1344, 256, 0, stream>>>(wi, wh, wiT, whF);
  k_embed<<<1000, 256, 0, stream>>>(states, actions, rewards, Ws, bs, Wa, ba, Wr, br, x);
  k_gx   <<<4000, 512, 0, stream>>>(x, wiT, bg, gx);
  k_gru  <<<16, 512, 0, stream>>>(gx, whF, (float*)d_out);
}

// Round 17
// 3401.093 us; speedup vs baseline: 1.6011x; 1.6011x over previous
//
#include <hip/hip_runtime.h>
#include <hip/hip_bf16.h>

#define TT   1000
#define BB   256
#define HID  256
#define GD   768
#define XD   192
#define NROW (TT*BB)

typedef __attribute__((ext_vector_type(8))) _Float16 half8;
typedef __attribute__((ext_vector_type(4))) float    float4_t;
typedef __attribute__((ext_vector_type(2))) unsigned uint2_t;

#define MFMA16(A,B,C) __builtin_amdgcn_mfma_f32_16x16x32_f16((A),(B),(C),0,0,0)

// AGPRs a0-a127 are asm-owned: wr -> a0..a63, wa -> a64..a127 (fixed, written
// once, read directly by MFMA - zero copies, zero streaming). wz (16 frags) is
// streamed per step via position-pinned ASM loads (r16 lesson: plain loads sink
// across sched_barrier; asm loads cannot). Pool: 128 arch + 128 agpr = 256/wave
// x 8 waves = 2048 = full pool (launches: r14 proof).
#define ACLOB \
  "a0","a1","a2","a3","a4","a5","a6","a7","a8","a9","a10","a11","a12","a13","a14","a15", \
  "a16","a17","a18","a19","a20","a21","a22","a23","a24","a25","a26","a27","a28","a29","a30","a31", \
  "a32","a33","a34","a35","a36","a37","a38","a39","a40","a41","a42","a43","a44","a45","a46","a47", \
  "a48","a49","a50","a51","a52","a53","a54","a55","a56","a57","a58","a59","a60","a61","a62","a63", \
  "a64","a65","a66","a67","a68","a69","a70","a71","a72","a73","a74","a75","a76","a77","a78","a79", \
  "a80","a81","a82","a83","a84","a85","a86","a87","a88","a89","a90","a91","a92","a93","a94","a95", \
  "a96","a97","a98","a99","a100","a101","a102","a103","a104","a105","a106","a107","a108","a109","a110","a111", \
  "a112","a113","a114","a115","a116","a117","a118","a119","a120","a121","a122","a123","a124","a125","a126","a127"

union h8u4 { half8 h; unsigned u[4]; };

__device__ __forceinline__ void gll16(const void* g, void* l) {
  __builtin_amdgcn_global_load_lds((const __attribute__((address_space(1))) void*)g,
                                   (__attribute__((address_space(3))) void*)l, 16, 0, 0);
}

__device__ __forceinline__ unsigned short f2h(float f) {
  _Float16 h = (_Float16)f;                       // RTN-even
  union { _Float16 h; unsigned short u; } c; c.h = h; return c.u;
}
__device__ __forceinline__ uint2_t pk4h(float4_t v) {
  union { _Float16 h[4]; uint2_t u; } c;
  c.h[0] = (_Float16)v.x; c.h[1] = (_Float16)v.y;
  c.h[2] = (_Float16)v.z; c.h[3] = (_Float16)v.w;
  return c.u;
}
__device__ __forceinline__ float4_t h4_to_f4(uint2_t v) {
  union { uint2_t u; _Float16 h[4]; } c; c.u = v;
  float4_t f;
  f.x = (float)c.h[0]; f.y = (float)c.h[1];
  f.z = (float)c.h[2]; f.w = (float)c.h[3];
  return f;
}
__device__ __forceinline__ float sigx(float x) {
  return __builtin_amdgcn_rcpf(1.0f + __builtin_amdgcn_exp2f(-1.4426950408889634f * x));
}
__device__ __forceinline__ float tanhx(float x) {
  return 1.0f - 2.0f * __builtin_amdgcn_rcpf(1.0f + __builtin_amdgcn_exp2f(2.8853900817779268f * x));
}
__device__ __forceinline__ float4_t sig4(float4_t v){ float4_t o; o.x=sigx(v.x); o.y=sigx(v.y); o.z=sigx(v.z); o.w=sigx(v.w); return o; }
__device__ __forceinline__ float4_t tanh4(float4_t v){ float4_t o; o.x=tanhx(v.x); o.y=tanhx(v.y); o.z=tanhx(v.z); o.w=tanhx(v.w); return o; }
__device__ __forceinline__ float gelu1(float v){
  // jax.nn.gelu default = tanh approximation
  float c = v + 0.044715f * v * v * v;
  float e = __builtin_amdgcn_exp2f((0.7978845608028654f * 2.8853900817779268f) * c);
  float th = 1.0f - 2.0f * __builtin_amdgcn_rcpf(1.0f + e);
  return 0.5f * v * (1.0f + th);
}

// ---------------- prep: wiT[n][k] fp16, whF pre-fragmented fp16 ----------------
__global__ void k_prep(const float* __restrict__ wi, const float* __restrict__ wh,
                       unsigned short* __restrict__ wiT, unsigned short* __restrict__ whF)
{
  int tid = blockIdx.x * 256 + threadIdx.x;
  if (tid < GD*XD) {
    int n = tid / XD, k = tid - n*XD;
    wiT[tid] = f2h(wi[(size_t)k*GD + n]);
  }
  int t2 = tid - GD*XD;
  if (t2 >= 0 && t2 < 48*8*64*8) {
    int j = t2 & 7, l = (t2 >> 3) & 63, f = t2 >> 9;
    int mf = f >> 3, kf = f & 7;
    int k = kf*32 + ((l >> 4) << 3) + j;   // A-frag: lane row=l&15 (=ocol), k=(l>>4)*8+j
    int n = (mf << 4) + (l & 15);
    whF[t2] = f2h(wh[(size_t)k*GD + n]);
  }
}

// ---------------- embeddings -> x fp16 [NROW][192] ----------------
__global__ void k_embed(const float* __restrict__ st, const float* __restrict__ ac,
                        const float* __restrict__ rw,
                        const float* __restrict__ Ws, const float* __restrict__ bs,
                        const float* __restrict__ Wa, const float* __restrict__ ba,
                        const float* __restrict__ Wr, const float* __restrict__ br,
                        unsigned short* __restrict__ x)
{
  int lane = threadIdx.x & 63;
  int wid = blockIdx.x * (blockDim.x >> 6) + (threadIdx.x >> 6);
  int nw  = gridDim.x * (blockDim.x >> 6);
  float wsr[64], war[8];
  #pragma unroll
  for (int k = 0; k < 64; ++k) wsr[k] = Ws[k*64 + lane];   // lane j holds Ws[:,j]
  #pragma unroll
  for (int k = 0; k < 8; ++k) war[k] = Wa[k*64 + lane];
  float wrr = Wr[lane];
  float bsv = bs[lane], bav = ba[lane], brv = br[lane];
  for (int row = wid; row < NROW; row += nw) {
    const float4_t* sp = (const float4_t*)(st + (size_t)row*64);
    float a0 = bsv;
    #pragma unroll
    for (int q = 0; q < 16; ++q) {
      float4_t v = sp[q];
      a0 = fmaf(v.x, wsr[4*q+0], a0);
      a0 = fmaf(v.y, wsr[4*q+1], a0);
      a0 = fmaf(v.z, wsr[4*q+2], a0);
      a0 = fmaf(v.w, wsr[4*q+3], a0);
    }
    const float4_t* ap = (const float4_t*)(ac + (size_t)row*8);
    float a1 = bav;
    #pragma unroll
    for (int q = 0; q < 2; ++q) {
      float4_t v = ap[q];
      a1 = fmaf(v.x, war[4*q+0], a1);
      a1 = fmaf(v.y, war[4*q+1], a1);
      a1 = fmaf(v.z, war[4*q+2], a1);
      a1 = fmaf(v.w, war[4*q+3], a1);
    }
    float a2 = fmaf(rw[row], wrr, brv);
    unsigned short* xr = x + (size_t)row*XD;
    xr[lane]       = f2h(gelu1(a0));
    xr[64 + lane]  = f2h(gelu1(a1));
    xr[128 + lane] = f2h(gelu1(a2));
  }
}

// ---------------- gx = x @ wi + bg (fp16), FRAGMENT-LINEAR output ----------------
__global__ __launch_bounds__(512, 2) void k_gx(const unsigned short* __restrict__ x,
                                               const unsigned short* __restrict__ wiT,
                                               const float* __restrict__ bg,
                                               unsigned short* __restrict__ gx)
{
  __shared__ half8 Xs[24*64];   // 24 B-frags (nf*6+kf), lane-linear
  __shared__ half8 As[16*64];   // 16 A-frags per stage phase
  int lane = threadIdx.x & 63;
  int wv   = threadIdx.x >> 6;
  int b    = lane & 15;
  int g8   = (lane >> 4) << 3;
  int row0 = blockIdx.x * 64;
  #pragma unroll
  for (int i = 0; i < 3; ++i) {
    int c = wv*3 + i, nf = c / 6, kf = c - nf*6;
    gll16(x + (size_t)(row0 + nf*16 + b)*XD + kf*32 + g8, &Xs[c*64]);
  }
  int g4 = g8 >> 1;
  float4_t acc[6][4];
  #pragma unroll
  for (int i = 0; i < 6; ++i) {
    float4_t bgv = *(const float4_t*)(bg + (wv + 8*i)*16 + g4);
    #pragma unroll
    for (int nf = 0; nf < 4; ++nf) acc[i][nf] = bgv;   // bias folded into C-init
  }
  half8 xb[4];
  for (int kf = 0; kf < 6; ++kf) {
    #pragma unroll
    for (int p = 0; p < 3; ++p) {
      __syncthreads();                      // prev phase's reads done
      #pragma unroll
      for (int i2 = 0; i2 < 2; ++i2) {
        int q = wv*2 + i2;
        gll16(wiT + (size_t)((p*16 + q)*16 + b)*XD + kf*32 + g8, &As[q*64]);
      }
      __syncthreads();                      // stage complete (drains vmcnt)
      if (p == 0) {
        #pragma unroll
        for (int nf = 0; nf < 4; ++nf) xb[nf] = Xs[(nf*6 + kf)*64 + lane];
      }
      half8 af0 = As[wv*64 + lane];
      half8 af1 = As[(wv+8)*64 + lane];
      #pragma unroll
      for (int nf = 0; nf < 4; ++nf) {
        acc[2*p  ][nf] = MFMA16(af0, xb[nf], acc[2*p  ][nf]);
        acc[2*p+1][nf] = MFMA16(af1, xb[nf], acc[2*p+1][nf]);
      }
    }
  }
  char* gxc = (char*)gx;
  #pragma unroll
  for (int i = 0; i < 6; ++i) {
    #pragma unroll
    for (int nf = 0; nf < 4; ++nf) {
      size_t idx = (((size_t)blockIdx.x*48 + (wv + 8*i))*4 + nf)*512 + lane*8;
      *(uint2_t*)(gxc + idx) = pk4h(acc[i][nf]);
    }
  }
}

// ---------------- GRU recurrence v11: wr+wa in fixed a0-a127, wz asm-streamed ----------------
// Queue invariant per step: [store2][wz16][gll3]. TOP waits vmcnt(2) (glls of
// this step's slab done, stores float). wz loads = volatile asm (cannot sink;
// r16 lesson) with SHORT live range (top -> phase-1 start, minimal spill risk).
// Phase-1 block 1 opens with counted s_waitcnt vmcnt(3): drains stores+wz,
// leaves glls in flight for the whole step. Phase 2 touches no vmcnt at all
// (wa read directly from a64-a127; r14-proven machinery).
__global__
__attribute__((amdgpu_flat_work_group_size(512, 512), amdgpu_waves_per_eu(2, 2)))
void k_gru(const unsigned short* __restrict__ gx,
           const unsigned short* __restrict__ whF,
           float* __restrict__ out)
{
  __shared__ char smem[98304];     // STATIC (1 WG/CU): h 8448 + rh 8448 + 2x24576 slabs
  char* h_lds  = smem;             // [16][264] fp16: row stride 528 B
  char* rh_lds = smem + 8448;
  char* gxb    = smem + 16896;     // 2 x 24576 B frag-linear slab
  const int tid  = threadIdx.x;
  const int lane = tid & 63;
  const int wv   = tid >> 6;
  const int wg   = blockIdx.x;
  const int b    = lane & 15;
  const int g    = lane >> 4;
  const int kr4  = g << 2;
  const int g16  = g << 4;

  // ---- pin wr -> a0..a63, wa -> a64..a127 (once) ----
#define PIN(FK, S0,S1,S2,S3) do { h8u4 _c; \
    _c.h = *(const half8*)(whF + ((size_t)((FK)*64 + lane) << 3)); \
    asm volatile("v_accvgpr_write_b32 a" S0 ", %0\n\t" \
                 "v_accvgpr_write_b32 a" S1 ", %1\n\t" \
                 "v_accvgpr_write_b32 a" S2 ", %2\n\t" \
                 "v_accvgpr_write_b32 a" S3 ", %3" \
                 :: "v"(_c.u[0]), "v"(_c.u[1]), "v"(_c.u[2]), "v"(_c.u[3]) : ACLOB); } while(0)
  // wr0 -> a0..a31   (FK = 128 + 16*wv + kf)
  PIN(128+16*wv+0, "0","1","2","3");     PIN(128+16*wv+1, "4","5","6","7");
  PIN(128+16*wv+2, "8","9","10","11");   PIN(128+16*wv+3, "12","13","14","15");
  PIN(128+16*wv+4, "16","17","18","19"); PIN(128+16*wv+5, "20","21","22","23");
  PIN(128+16*wv+6, "24","25","26","27"); PIN(128+16*wv+7, "28","29","30","31");
  // wr1 -> a32..a63  (FK = 136 + 16*wv + kf)
  PIN(136+16*wv+0, "32","33","34","35"); PIN(136+16*wv+1, "36","37","38","39");
  PIN(136+16*wv+2, "40","41","42","43"); PIN(136+16*wv+3, "44","45","46","47");
  PIN(136+16*wv+4, "48","49","50","51"); PIN(136+16*wv+5, "52","53","54","55");
  PIN(136+16*wv+6, "56","57","58","59"); PIN(136+16*wv+7, "60","61","62","63");
  // wa0 -> a64..a95  (FK = 256 + 16*wv + kf)
  PIN(256+16*wv+0, "64","65","66","67");   PIN(256+16*wv+1, "68","69","70","71");
  PIN(256+16*wv+2, "72","73","74","75");   PIN(256+16*wv+3, "76","77","78","79");
  PIN(256+16*wv+4, "80","81","82","83");   PIN(256+16*wv+5, "84","85","86","87");
  PIN(256+16*wv+6, "88","89","90","91");   PIN(256+16*wv+7, "92","93","94","95");
  // wa1 -> a96..a127 (FK = 264 + 16*wv + kf)
  PIN(264+16*wv+0, "96","97","98","99");    PIN(264+16*wv+1, "100","101","102","103");
  PIN(264+16*wv+2, "104","105","106","107");PIN(264+16*wv+3, "108","109","110","111");
  PIN(264+16*wv+4, "112","113","114","115");PIN(264+16*wv+5, "116","117","118","119");
  PIN(264+16*wv+6, "120","121","122","123");PIN(264+16*wv+7, "124","125","126","127");
#undef PIN

  for (int i = tid; i < 2112; i += 512) ((unsigned*)h_lds)[i] = 0u;   // h0 = 0 (8448 B)

  // wz stream bases: frags FK = 16*wv + 0..15 are CONTIGUOUS 16 KB at
  // whF + ((16*wv*64 + lane) << 3). 4 bases, 4 frags each (imm offset 0..3072).
  const unsigned long long wzb0 =
      (unsigned long long)(const char*)(whF + ((size_t)((16*wv)*64 + lane) << 3));
  const unsigned long long wzb1 = wzb0 + 4096;
  const unsigned long long wzb2 = wzb0 + 8192;
  const unsigned long long wzb3 = wzb0 + 12288;

  // slab staging: frag-linear (see k_gx). Dest D = i*8192 + tid*16.
  const int nf   = wg & 3;
  const int bsel = wg >> 2;
  int soff[3], dch[3];
  #pragma unroll
  for (int i = 0; i < 3; ++i) {
    int c = i*16 + (tid >> 5);
    int r = (tid & 31) << 4;
    soff[i] = nf*512 + c*2048 + r;
    dch[i]  = i*8192 + tid*16;
  }
  const char* gxc = (const char*)gx;
  #pragma unroll
  for (int i = 0; i < 3; ++i)
    gll16(gxc + (size_t)bsel*98304 + soff[i], gxb + dch[i]);
  __syncthreads();   // full drain: t=0 slab ready, h zeroed, pins done

  float4_t hf0 = {0.f, 0.f, 0.f, 0.f}, hf1 = hf0;   // fp32 h for owned cols
  const char* hb_base = h_lds + b*528;
  const char* rb_base = rh_lds + b*528;
  const int off_h0 = (wv*32 + kr4) << 1;
  const int off_h1 = off_h0 + 32;
  const int lz0 = ( 2*wv    )*512 + lane*8;
  const int lz1 = ( 2*wv + 1)*512 + lane*8;
  const int lr0 = (16 + 2*wv)*512 + lane*8;
  const int lr1 = (17 + 2*wv)*512 + lane*8;
  const int la0 = (32 + 2*wv)*512 + lane*8;
  const int la1 = (33 + 2*wv)*512 + lane*8;

  for (int t = 0; t < TT; ++t) {
    // TOP barrier: vmcnt(2) -> this step's slab glls done; 2 out-stores float
    asm volatile("s_waitcnt vmcnt(2) lgkmcnt(0)" ::: "memory", ACLOB);
    __builtin_amdgcn_s_barrier();
    asm volatile("" ::: "memory");

    // wz stream: 16 position-pinned asm loads. Queue: [store2][wz16].
    half8 za0, za1, za2, za3, za4, za5, za6, za7;   // wz0 kf0..7
    half8 zb0, zb1, zb2, zb3, zb4, zb5, zb6, zb7;   // wz1 kf0..7
    asm volatile("global_load_dwordx4 %0, %1, off"             : "=v"(za0) : "v"(wzb0));
    asm volatile("global_load_dwordx4 %0, %1, off offset:1024" : "=v"(za1) : "v"(wzb0));
    asm volatile("global_load_dwordx4 %0, %1, off offset:2048" : "=v"(za2) : "v"(wzb0));
    asm volatile("global_load_dwordx4 %0, %1, off offset:3072" : "=v"(za3) : "v"(wzb0));
    asm volatile("global_load_dwordx4 %0, %1, off"             : "=v"(za4) : "v"(wzb1));
    asm volatile("global_load_dwordx4 %0, %1, off offset:1024" : "=v"(za5) : "v"(wzb1));
    asm volatile("global_load_dwordx4 %0, %1, off offset:2048" : "=v"(za6) : "v"(wzb1));
    asm volatile("global_load_dwordx4 %0, %1, off offset:3072" : "=v"(za7) : "v"(wzb1));
    asm volatile("global_load_dwordx4 %0, %1, off"             : "=v"(zb0) : "v"(wzb2));
    asm volatile("global_load_dwordx4 %0, %1, off offset:1024" : "=v"(zb1) : "v"(wzb2));
    asm volatile("global_load_dwordx4 %0, %1, off offset:2048" : "=v"(zb2) : "v"(wzb2));
    asm volatile("global_load_dwordx4 %0, %1, off offset:3072" : "=v"(zb3) : "v"(wzb2));
    asm volatile("global_load_dwordx4 %0, %1, off"             : "=v"(zb4) : "v"(wzb3));
    asm volatile("global_load_dwordx4 %0, %1, off offset:1024" : "=v"(zb5) : "v"(wzb3));
    asm volatile("global_load_dwordx4 %0, %1, off offset:2048" : "=v"(zb6) : "v"(wzb3));
    asm volatile("global_load_dwordx4 %0, %1, off offset:3072" : "=v"(zb7) : "v"(wzb3));

    // slab prefetch (ALWAYS 3 glls; dummy self-slab on last step keeps counts
    // uniform). Queue: [store2][wz16][gll3].
    {
      int tn = (t + 1 < TT) ? (t + 1) : t;
      const char* slab = gxc + ((size_t)tn*4 + bsel)*98304;
      char* dstb = gxb + 24576*((t+1) & 1);
      #pragma unroll
      for (int i = 0; i < 3; ++i) gll16(slab + soff[i], dstb + dch[i]);
    }

    const char* cur = gxb + 24576*(t & 1);
    // ---- phase 1: zr^T = sigmoid(gx_zr + wh_zr^T @ h^T) ----
    float4_t az0 = h4_to_f4(*(const uint2_t*)(cur + lz0));
    float4_t az1 = h4_to_f4(*(const uint2_t*)(cur + lz1));
    float4_t ar0 = h4_to_f4(*(const uint2_t*)(cur + lr0));
    float4_t ar1 = h4_to_f4(*(const uint2_t*)(cur + lr1));
    half8 hb0 = *(const half8*)(hb_base + 0*64 + g16);
    half8 hb1 = *(const half8*)(hb_base + 1*64 + g16);
    // block 1 (kf 0,1): counted wait -> stores+wz drained, glls stay in flight
    asm volatile(
      "s_waitcnt vmcnt(3)\n\t"
      "s_nop 2\n\t"
      "v_mfma_f32_16x16x32_f16 %0, %4, %8, %0\n\t"
      "v_mfma_f32_16x16x32_f16 %1, %5, %8, %1\n\t"
      "v_mfma_f32_16x16x32_f16 %2, a[0:3], %8, %2\n\t"
      "v_mfma_f32_16x16x32_f16 %3, a[32:35], %8, %3\n\t"
      "v_mfma_f32_16x16x32_f16 %0, %6, %9, %0\n\t"
      "v_mfma_f32_16x16x32_f16 %1, %7, %9, %1\n\t"
      "v_mfma_f32_16x16x32_f16 %2, a[4:7], %9, %2\n\t"
      "v_mfma_f32_16x16x32_f16 %3, a[36:39], %9, %3"
      : "+v"(az0), "+v"(az1), "+v"(ar0), "+v"(ar1)
      : "v"(za0), "v"(zb0), "v"(za1), "v"(zb1), "v"(hb0), "v"(hb1)
      : ACLOB);
    half8 hb2 = *(const half8*)(hb_base + 2*64 + g16);
    half8 hb3 = *(const half8*)(hb_base + 3*64 + g16);
    asm volatile(
      "v_mfma_f32_16x16x32_f16 %0, %4, %8, %0\n\t"
      "v_mfma_f32_16x16x32_f16 %1, %5, %8, %1\n\t"
      "v_mfma_f32_16x16x32_f16 %2, a[8:11], %8, %2\n\t"
      "v_mfma_f32_16x16x32_f16 %3, a[40:43], %8, %3\n\t"
      "v_mfma_f32_16x16x32_f16 %0, %6, %9, %0\n\t"
      "v_mfma_f32_16x16x32_f16 %1, %7, %9, %1\n\t"
      "v_mfma_f32_16x16x32_f16 %2, a[12:15], %9, %2\n\t"
      "v_mfma_f32_16x16x32_f16 %3, a[44:47], %9, %3"
      : "+v"(az0), "+v"(az1), "+v"(ar0), "+v"(ar1)
      : "v"(za2), "v"(zb2), "v"(za3), "v"(zb3), "v"(hb2), "v"(hb3)
      : ACLOB);
    half8 hb4 = *(const half8*)(hb_base + 4*64 + g16);
    half8 hb5 = *(const half8*)(hb_base + 5*64 + g16);
    asm volatile(
      "v_mfma_f32_16x16x32_f16 %0, %4, %8, %0\n\t"
      "v_mfma_f32_16x16x32_f16 %1, %5, %8, %1\n\t"
      "v_mfma_f32_16x16x32_f16 %2, a[16:19], %8, %2\n\t"
      "v_mfma_f32_16x16x32_f16 %3, a[48:51], %8, %3\n\t"
      "v_mfma_f32_16x16x32_f16 %0, %6, %9, %0\n\t"
      "v_mfma_f32_16x16x32_f16 %1, %7, %9, %1\n\t"
      "v_mfma_f32_16x16x32_f16 %2, a[20:23], %9, %2\n\t"
      "v_mfma_f32_16x16x32_f16 %3, a[52:55], %9, %3"
      : "+v"(az0), "+v"(az1), "+v"(ar0), "+v"(ar1)
      : "v"(za4), "v"(zb4), "v"(za5), "v"(zb5), "v"(hb4), "v"(hb5)
      : ACLOB);
    half8 hb6 = *(const half8*)(hb_base + 6*64 + g16);
    half8 hb7 = *(const half8*)(hb_base + 7*64 + g16);
    asm volatile(
      "v_mfma_f32_16x16x32_f16 %0, %4, %8, %0\n\t"
      "v_mfma_f32_16x16x32_f16 %1, %5, %8, %1\n\t"
      "v_mfma_f32_16x16x32_f16 %2, a[24:27], %8, %2\n\t"
      "v_mfma_f32_16x16x32_f16 %3, a[56:59], %8, %3\n\t"
      "v_mfma_f32_16x16x32_f16 %0, %6, %9, %0\n\t"
      "v_mfma_f32_16x16x32_f16 %1, %7, %9, %1\n\t"
      "v_mfma_f32_16x16x32_f16 %2, a[28:31], %9, %2\n\t"
      "v_mfma_f32_16x16x32_f16 %3, a[60:63], %9, %3\n\t"
      "s_nop 7\n\t"
      "s_nop 7"
      : "+v"(az0), "+v"(az1), "+v"(ar0), "+v"(ar1)
      : "v"(za6), "v"(zb6), "v"(za7), "v"(zb7), "v"(hb6), "v"(hb7)
      : ACLOB);
    float4_t z0 = sig4(az0), z1 = sig4(az1);
    float4_t rh0 = sig4(ar0) * hf0, rh1 = sig4(ar1) * hf1;   // r*h, all in-lane
    *(uint2_t*)(rh_lds + b*528 + off_h0) = pk4h(rh0);
    *(uint2_t*)(rh_lds + b*528 + off_h1) = pk4h(rh1);
    // MID barrier: LDS-only wait, glls stay outstanding
    asm volatile("s_waitcnt lgkmcnt(0)" ::: "memory", ACLOB);
    __builtin_amdgcn_s_barrier();
    asm volatile("" ::: "memory");
    // ---- phase 2: a^T = tanh(gx_a + wh_a^T @ (r*h)^T), wa from a64-a127 ----
    float4_t aa0 = h4_to_f4(*(const uint2_t*)(cur + la0));
    float4_t aa1 = h4_to_f4(*(const uint2_t*)(cur + la1));
    half8 rb0 = *(const half8*)(rb_base + 0*64 + g16);
    half8 rb1 = *(const half8*)(rb_base + 1*64 + g16);
    half8 rb2 = *(const half8*)(rb_base + 2*64 + g16);
    half8 rb3 = *(const half8*)(rb_base + 3*64 + g16);
    asm volatile(
      "s_nop 2\n\t"
      "v_mfma_f32_16x16x32_f16 %0, a[64:67], %2, %0\n\t"
      "v_mfma_f32_16x16x32_f16 %1, a[96:99], %2, %1\n\t"
      "v_mfma_f32_16x16x32_f16 %0, a[68:71], %3, %0\n\t"
      "v_mfma_f32_16x16x32_f16 %1, a[100:103], %3, %1\n\t"
      "v_mfma_f32_16x16x32_f16 %0, a[72:75], %4, %0\n\t"
      "v_mfma_f32_16x16x32_f16 %1, a[104:107], %4, %1\n\t"
      "v_mfma_f32_16x16x32_f16 %0, a[76:79], %5, %0\n\t"
      "v_mfma_f32_16x16x32_f16 %1, a[108:111], %5, %1"
      : "+v"(aa0), "+v"(aa1)
      : "v"(rb0), "v"(rb1), "v"(rb2), "v"(rb3)
      : ACLOB);
    half8 rb4 = *(const half8*)(rb_base + 4*64 + g16);
    half8 rb5 = *(const half8*)(rb_base + 5*64 + g16);
    half8 rb6 = *(const half8*)(rb_base + 6*64 + g16);
    half8 rb7 = *(const half8*)(rb_base + 7*64 + g16);
    asm volatile(
      "v_mfma_f32_16x16x32_f16 %0, a[80:83], %2, %0\n\t"
      "v_mfma_f32_16x16x32_f16 %1, a[112:115], %2, %1\n\t"
      "v_mfma_f32_16x16x32_f16 %0, a[84:87], %3, %0\n\t"
      "v_mfma_f32_16x16x32_f16 %1, a[116:119], %3, %1\n\t"
      "v_mfma_f32_16x16x32_f16 %0, a[88:91], %4, %0\n\t"
      "v_mfma_f32_16x16x32_f16 %1, a[120:123], %4, %1\n\t"
      "v_mfma_f32_16x16x32_f16 %0, a[92:95], %5, %0\n\t"
      "v_mfma_f32_16x16x32_f16 %1, a[124:127], %5, %1\n\t"
      "s_nop 7\n\t"
      "s_nop 7"
      : "+v"(aa0), "+v"(aa1)
      : "v"(rb4), "v"(rb5), "v"(rb6), "v"(rb7)
      : ACLOB);
    float4_t a0 = tanh4(aa0), a1 = tanh4(aa1);
    float4_t hn0 = hf0 + z0 * (a0 - hf0);   // (1-z)h + z*a
    float4_t hn1 = hf1 + z1 * (a1 - hf1);
    hf0 = hn0; hf1 = hn1;
    *(uint2_t*)(h_lds + b*528 + off_h0) = pk4h(hn0);
    *(uint2_t*)(h_lds + b*528 + off_h1) = pk4h(hn1);
    float* op = out + (((size_t)t*BB + wg*16 + b) << 8) + wv*32 + kr4;
    *(float4_t*)op = hn0;
    *(float4_t*)(op + 16) = hn1;
  }
}

extern "C" void kernel_launch(void* const* d_in, const int* in_sizes, int n_in,
                              void* d_out, int out_size, void* d_ws, size_t ws_size,
                              hipStream_t stream) {
  (void)in_sizes; (void)n_in; (void)out_size; (void)ws_size;
  const float* states  = (const float*)d_in[0];
  const float* actions = (const float*)d_in[1];
  const float* rewards = (const float*)d_in[2];
  const float* Ws = (const float*)d_in[3];
  const float* bs = (const float*)d_in[4];
  const float* Wa = (const float*)d_in[5];
  const float* ba = (const float*)d_in[6];
  const float* Wr = (const float*)d_in[7];
  const float* br = (const float*)d_in[8];
  const float* wi = (const float*)d_in[9];
  const float* wh = (const float*)d_in[10];
  const float* bg = (const float*)d_in[11];
  char* wsb = (char*)d_ws;
  // workspace layout (requires ~492.3 MB):
  unsigned short* gx  = (unsigned short*)(wsb);                   // 393,216,000 B
  unsigned short* x   = (unsigned short*)(wsb + 393216000LL);     //  98,304,000 B
  unsigned short* wiT = (unsigned short*)(wsb + 491520000LL);     //     294,912 B
  unsigned short* whF = (unsigned short*)(wsb + 491814912LL);     //     393,216 B
  k_prep <<<1344, 256, 0, stream>>>(wi, wh, wiT, whF);
  k_embed<<<1000, 256, 0, stream>>>(states, actions, rewards, Ws, bs, Wa, ba, Wr, br, x);
  k_gx   <<<4000, 512, 0, stream>>>(x, wiT, bg, gx);
  k_gru  <<<16, 512, 0, stream>>>(gx, whF, (float*)d_out);
}

// Round 18
// 2186.048 us; speedup vs baseline: 2.4910x; 1.5558x over previous
//
#include <hip/hip_runtime.h>
#include <hip/hip_bf16.h>

#define TT   1000
#define BB   256
#define HID  256
#define GD   768
#define XD   192
#define NROW (TT*BB)

typedef __attribute__((ext_vector_type(8))) _Float16 half8;
typedef __attribute__((ext_vector_type(4))) float    float4_t;
typedef __attribute__((ext_vector_type(2))) unsigned uint2_t;

#define MFMA16(A,B,C) __builtin_amdgcn_mfma_f32_16x16x32_f16((A),(B),(C),0,0,0)

__device__ __forceinline__ void gll16(const void* g, void* l) {
  __builtin_amdgcn_global_load_lds((const __attribute__((address_space(1))) void*)g,
                                   (__attribute__((address_space(3))) void*)l, 16, 0, 0);
}

__device__ __forceinline__ unsigned short f2h(float f) {
  _Float16 h = (_Float16)f;                       // RTN-even
  union { _Float16 h; unsigned short u; } c; c.h = h; return c.u;
}
__device__ __forceinline__ uint2_t pk4h(float4_t v) {
  union { _Float16 h[4]; uint2_t u; } c;
  c.h[0] = (_Float16)v.x; c.h[1] = (_Float16)v.y;
  c.h[2] = (_Float16)v.z; c.h[3] = (_Float16)v.w;
  return c.u;
}
__device__ __forceinline__ float4_t h4_to_f4(uint2_t v) {
  union { uint2_t u; _Float16 h[4]; } c; c.u = v;
  float4_t f;
  f.x = (float)c.h[0]; f.y = (float)c.h[1];
  f.z = (float)c.h[2]; f.w = (float)c.h[3];
  return f;
}
__device__ __forceinline__ float sigx(float x) {
  return __builtin_amdgcn_rcpf(1.0f + __builtin_amdgcn_exp2f(-1.4426950408889634f * x));
}
__device__ __forceinline__ float tanhx(float x) {
  return 1.0f - 2.0f * __builtin_amdgcn_rcpf(1.0f + __builtin_amdgcn_exp2f(2.8853900817779268f * x));
}
__device__ __forceinline__ float4_t sig4(float4_t v){ float4_t o; o.x=sigx(v.x); o.y=sigx(v.y); o.z=sigx(v.z); o.w=sigx(v.w); return o; }
__device__ __forceinline__ float4_t tanh4(float4_t v){ float4_t o; o.x=tanhx(v.x); o.y=tanhx(v.y); o.z=tanhx(v.z); o.w=tanhx(v.w); return o; }
__device__ __forceinline__ float gelu1(float v){
  // jax.nn.gelu default = tanh approximation
  float c = v + 0.044715f * v * v * v;
  float e = __builtin_amdgcn_exp2f((0.7978845608028654f * 2.8853900817779268f) * c);
  float th = 1.0f - 2.0f * __builtin_amdgcn_rcpf(1.0f + e);
  return 0.5f * v * (1.0f + th);
}

// ---------------- prep: wiT[n][k] fp16, whF pre-fragmented fp16 ----------------
__global__ void k_prep(const float* __restrict__ wi, const float* __restrict__ wh,
                       unsigned short* __restrict__ wiT, unsigned short* __restrict__ whF)
{
  int tid = blockIdx.x * 256 + threadIdx.x;
  if (tid < GD*XD) {
    int n = tid / XD, k = tid - n*XD;
    wiT[tid] = f2h(wi[(size_t)k*GD + n]);
  }
  int t2 = tid - GD*XD;
  if (t2 >= 0 && t2 < 48*8*64*8) {
    int j = t2 & 7, l = (t2 >> 3) & 63, f = t2 >> 9;
    int mf = f >> 3, kf = f & 7;
    int k = kf*32 + ((l >> 4) << 3) + j;   // A-frag: lane row=l&15 (=ocol), k=(l>>4)*8+j
    int n = (mf << 4) + (l & 15);
    whF[t2] = f2h(wh[(size_t)k*GD + n]);
  }
}

// ---------------- embeddings -> x fp16 [NROW][192] ----------------
__global__ void k_embed(const float* __restrict__ st, const float* __restrict__ ac,
                        const float* __restrict__ rw,
                        const float* __restrict__ Ws, const float* __restrict__ bs,
                        const float* __restrict__ Wa, const float* __restrict__ ba,
                        const float* __restrict__ Wr, const float* __restrict__ br,
                        unsigned short* __restrict__ x)
{
  int lane = threadIdx.x & 63;
  int wid = blockIdx.x * (blockDim.x >> 6) + (threadIdx.x >> 6);
  int nw  = gridDim.x * (blockDim.x >> 6);
  float wsr[64], war[8];
  #pragma unroll
  for (int k = 0; k < 64; ++k) wsr[k] = Ws[k*64 + lane];   // lane j holds Ws[:,j]
  #pragma unroll
  for (int k = 0; k < 8; ++k) war[k] = Wa[k*64 + lane];
  float wrr = Wr[lane];
  float bsv = bs[lane], bav = ba[lane], brv = br[lane];
  for (int row = wid; row < NROW; row += nw) {
    const float4_t* sp = (const float4_t*)(st + (size_t)row*64);
    float a0 = bsv;
    #pragma unroll
    for (int q = 0; q < 16; ++q) {
      float4_t v = sp[q];
      a0 = fmaf(v.x, wsr[4*q+0], a0);
      a0 = fmaf(v.y, wsr[4*q+1], a0);
      a0 = fmaf(v.z, wsr[4*q+2], a0);
      a0 = fmaf(v.w, wsr[4*q+3], a0);
    }
    const float4_t* ap = (const float4_t*)(ac + (size_t)row*8);
    float a1 = bav;
    #pragma unroll
    for (int q = 0; q < 2; ++q) {
      float4_t v = ap[q];
      a1 = fmaf(v.x, war[4*q+0], a1);
      a1 = fmaf(v.y, war[4*q+1], a1);
      a1 = fmaf(v.z, war[4*q+2], a1);
      a1 = fmaf(v.w, war[4*q+3], a1);
    }
    float a2 = fmaf(rw[row], wrr, brv);
    unsigned short* xr = x + (size_t)row*XD;
    xr[lane]       = f2h(gelu1(a0));
    xr[64 + lane]  = f2h(gelu1(a1));
    xr[128 + lane] = f2h(gelu1(a2));
  }
}

// ---------------- gx = x @ wi + bg (fp16), FRAGMENT-LINEAR output ----------------
// Fragment (block, c, nf) -> contiguous 512 B chunk at
// ((block*48 + c)*4 + nf)*512 + lane*8.  Store = 64 lanes x 8 B contiguous.
__global__ __launch_bounds__(512, 2) void k_gx(const unsigned short* __restrict__ x,
                                               const unsigned short* __restrict__ wiT,
                                               const float* __restrict__ bg,
                                               unsigned short* __restrict__ gx)
{
  __shared__ half8 Xs[24*64];   // 24 B-frags (nf*6+kf), lane-linear
  __shared__ half8 As[16*64];   // 16 A-frags per stage phase
  int lane = threadIdx.x & 63;
  int wv   = threadIdx.x >> 6;
  int b    = lane & 15;
  int g8   = (lane >> 4) << 3;
  int row0 = blockIdx.x * 64;
  #pragma unroll
  for (int i = 0; i < 3; ++i) {
    int c = wv*3 + i, nf = c / 6, kf = c - nf*6;
    gll16(x + (size_t)(row0 + nf*16 + b)*XD + kf*32 + g8, &Xs[c*64]);
  }
  int g4 = g8 >> 1;
  float4_t acc[6][4];
  #pragma unroll
  for (int i = 0; i < 6; ++i) {
    float4_t bgv = *(const float4_t*)(bg + (wv + 8*i)*16 + g4);
    #pragma unroll
    for (int nf = 0; nf < 4; ++nf) acc[i][nf] = bgv;   // bias folded into C-init
  }
  half8 xb[4];
  for (int kf = 0; kf < 6; ++kf) {
    #pragma unroll
    for (int p = 0; p < 3; ++p) {
      __syncthreads();                      // prev phase's reads done
      #pragma unroll
      for (int i2 = 0; i2 < 2; ++i2) {
        int q = wv*2 + i2;
        gll16(wiT + (size_t)((p*16 + q)*16 + b)*XD + kf*32 + g8, &As[q*64]);
      }
      __syncthreads();                      // stage complete (drains vmcnt)
      if (p == 0) {
        #pragma unroll
        for (int nf = 0; nf < 4; ++nf) xb[nf] = Xs[(nf*6 + kf)*64 + lane];
      }
      half8 af0 = As[wv*64 + lane];
      half8 af1 = As[(wv+8)*64 + lane];
      #pragma unroll
      for (int nf = 0; nf < 4; ++nf) {
        acc[2*p  ][nf] = MFMA16(af0, xb[nf], acc[2*p  ][nf]);
        acc[2*p+1][nf] = MFMA16(af1, xb[nf], acc[2*p+1][nf]);
      }
    }
  }
  char* gxc = (char*)gx;
  #pragma unroll
  for (int i = 0; i < 6; ++i) {
    #pragma unroll
    for (int nf = 0; nf < 4; ++nf) {
      size_t idx = (((size_t)blockIdx.x*48 + (wv + 8*i))*4 + nf)*512 + lane*8;
      *(uint2_t*)(gxc + idx) = pk4h(acc[i][nf]);
    }
  }
}

// ---------------- GRU recurrence (r12, empirical optimum of this design space) ----------------
// 8 waves, builtin MFMA, ~124 resident regs + compiler-pipelined L2 weight
// stream. Manual alternatives (AGPR pinning r13-r17) all lost more to
// serialization than the stream costs. Frag-linear slab + 528B-padded h/rh.
__global__
__attribute__((amdgpu_flat_work_group_size(512, 512), amdgpu_waves_per_eu(2, 2)))
void k_gru(const unsigned short* __restrict__ gx,
           const unsigned short* __restrict__ whF,
           float* __restrict__ out)
{
  __shared__ char smem[98304];     // STATIC (1 WG/CU): h 8448 + rh 8448 + 2x24576 slabs
  char* h_lds  = smem;             // [16][264] fp16: row stride 528 B
  char* rh_lds = smem + 8448;
  char* gxb    = smem + 16896;     // 2 x 24576 B frag-linear slab
  const int tid  = threadIdx.x;
  const int lane = tid & 63;
  const int wv   = tid >> 6;
  const int wg   = blockIdx.x;
  const int b    = lane & 15;
  const int g    = lane >> 4;
  const int kr4  = g << 2;

  // wave wv owns ocols [wv*32, wv*32+32) of z, r and a. 48 frags = 192 regs.
  half8 wz0[8], wz1[8], wr0[8], wr1[8], wa0[8], wa1[8];
  #pragma unroll
  for (int kf = 0; kf < 8; ++kf) {
    wz0[kf] = *(const half8*)(whF + ((size_t)((( 2*wv    )*8 + kf)*64 + lane) << 3));
    wz1[kf] = *(const half8*)(whF + ((size_t)((( 2*wv + 1)*8 + kf)*64 + lane) << 3));
    wr0[kf] = *(const half8*)(whF + ((size_t)(((16 + 2*wv)*8 + kf)*64 + lane) << 3));
    wr1[kf] = *(const half8*)(whF + ((size_t)(((17 + 2*wv)*8 + kf)*64 + lane) << 3));
    wa0[kf] = *(const half8*)(whF + ((size_t)(((32 + 2*wv)*8 + kf)*64 + lane) << 3));
    wa1[kf] = *(const half8*)(whF + ((size_t)(((33 + 2*wv)*8 + kf)*64 + lane) << 3));
  }
  #pragma unroll
  for (int kf = 0; kf < 8; ++kf) {
    asm volatile("" : "+v"(wz0[kf]));
    asm volatile("" : "+v"(wz1[kf]));
    asm volatile("" : "+v"(wr0[kf]));
    asm volatile("" : "+v"(wr1[kf]));
    asm volatile("" : "+v"(wa0[kf]));
    asm volatile("" : "+v"(wa1[kf]));
  }
  for (int i = tid; i < 2112; i += 512) ((unsigned*)h_lds)[i] = 0u;   // h0 = 0 (8448 B)

  // slab staging: frag-linear. Dest byte D = i*8192 + tid*16 (wave-uniform base
  // + lane*16). Source within the (bt,nf) block: c = D/512, r = D%512 ->
  // soff = nf*512 + c*2048 + r.
  const int nf   = wg & 3;
  const int bsel = wg >> 2;
  int soff[3], dch[3];
  #pragma unroll
  for (int i = 0; i < 3; ++i) {
    int c = i*16 + (tid >> 5);
    int r = (tid & 31) << 4;
    soff[i] = nf*512 + c*2048 + r;
    dch[i]  = i*8192 + tid*16;
  }
  const char* gxc = (const char*)gx;
  #pragma unroll
  for (int i = 0; i < 3; ++i)
    gll16(gxc + (size_t)bsel*98304 + soff[i], gxb + dch[i]);
  __syncthreads();   // full drain: t=0 slab ready, h zeroed

  float4_t hf0 = {0.f, 0.f, 0.f, 0.f}, hf1 = hf0;   // fp32 h for owned cols
  const char* hb_base = h_lds + b*528;
  const char* rb_base = rh_lds + b*528;
  const int off_h0 = (wv*32 + kr4) << 1;        // h/rh row-internal byte offset
  const int off_h1 = off_h0 + 32;
  const int lz0 = ( 2*wv    )*512 + lane*8;     // slab frag offsets (C-init)
  const int lz1 = ( 2*wv + 1)*512 + lane*8;
  const int lr0 = (16 + 2*wv)*512 + lane*8;
  const int lr1 = (17 + 2*wv)*512 + lane*8;
  const int la0 = (32 + 2*wv)*512 + lane*8;
  const int la1 = (33 + 2*wv)*512 + lane*8;

  for (int t = 0; t < TT; ++t) {
    // TOP barrier: counted vmcnt(2) -> 3 glls done, 2 hs-stores may stay in flight
    asm volatile("s_waitcnt vmcnt(2) lgkmcnt(0)" ::: "memory");
    __builtin_amdgcn_s_barrier();
    asm volatile("" ::: "memory");   // no memory op hoists above the barrier
    if (t + 1 < TT) {   // prefetch next slab; stays in flight across mid barrier
      const char* slab = gxc + ((size_t)(t+1)*4 + bsel)*98304;
      char* dstb = gxb + 24576*((t+1) & 1);
      #pragma unroll
      for (int i = 0; i < 3; ++i) gll16(slab + soff[i], dstb + dch[i]);
    }
    const char* cur = gxb + 24576*(t & 1);
    // ---- phase 1: zr^T = sigmoid(gx_zr + wh_zr^T @ h^T) ----
    float4_t az0 = h4_to_f4(*(const uint2_t*)(cur + lz0));
    float4_t az1 = h4_to_f4(*(const uint2_t*)(cur + lz1));
    float4_t ar0 = h4_to_f4(*(const uint2_t*)(cur + lr0));
    float4_t ar1 = h4_to_f4(*(const uint2_t*)(cur + lr1));
    #pragma unroll
    for (int kf = 0; kf < 8; ++kf) {
      half8 hb = *(const half8*)(hb_base + kf*64 + (g << 4));
      az0 = MFMA16(wz0[kf], hb, az0);
      az1 = MFMA16(wz1[kf], hb, az1);
      ar0 = MFMA16(wr0[kf], hb, ar0);
      ar1 = MFMA16(wr1[kf], hb, ar1);
    }
    float4_t z0 = sig4(az0), z1 = sig4(az1);
    float4_t rh0 = sig4(ar0) * hf0, rh1 = sig4(ar1) * hf1;   // r*h, all in-lane
    *(uint2_t*)(rh_lds + b*528 + off_h0) = pk4h(rh0);
    *(uint2_t*)(rh_lds + b*528 + off_h1) = pk4h(rh1);
    // MID barrier: LDS-only wait, prefetch glls stay outstanding
    asm volatile("s_waitcnt lgkmcnt(0)" ::: "memory");
    __builtin_amdgcn_s_barrier();
    asm volatile("" ::: "memory");
    // ---- phase 2: a^T = tanh(gx_a + wh_a^T @ (r*h)^T) ----
    float4_t aa0 = h4_to_f4(*(const uint2_t*)(cur + la0));
    float4_t aa1 = h4_to_f4(*(const uint2_t*)(cur + la1));
    #pragma unroll
    for (int kf = 0; kf < 8; ++kf) {
      half8 rb = *(const half8*)(rb_base + kf*64 + (g << 4));
      aa0 = MFMA16(wa0[kf], rb, aa0);
      aa1 = MFMA16(wa1[kf], rb, aa1);
    }
    float4_t a0 = tanh4(aa0), a1 = tanh4(aa1);
    float4_t hn0 = hf0 + z0 * (a0 - hf0);   // (1-z)h + z*a
    float4_t hn1 = hf1 + z1 * (a1 - hf1);
    hf0 = hn0; hf1 = hn1;
    *(uint2_t*)(h_lds + b*528 + off_h0) = pk4h(hn0);
    *(uint2_t*)(h_lds + b*528 + off_h1) = pk4h(hn1);
    float* op = out + (((size_t)t*BB + wg*16 + b) << 8) + wv*32 + kr4;
    *(float4_t*)op = hn0;
    *(float4_t*)(op + 16) = hn1;
  }
}

extern "C" void kernel_launch(void* const* d_in, const int* in_sizes, int n_in,
                              void* d_out, int out_size, void* d_ws, size_t ws_size,
                              hipStream_t stream) {
  (void)in_sizes; (void)n_in; (void)out_size; (void)ws_size;
  const float* states  = (const float*)d_in[0];
  const float* actions = (const float*)d_in[1];
  const float* rewards = (const float*)d_in[2];
  const float* Ws = (const float*)d_in[3];
  const float* bs = (const float*)d_in[4];
  const float* Wa = (const float*)d_in[5];
  const float* ba = (const float*)d_in[6];
  const float* Wr = (const float*)d_in[7];
  const float* br = (const float*)d_in[8];
  const float* wi = (const float*)d_in[9];
  const float* wh = (const float*)d_in[10];
  const float* bg = (const float*)d_in[11];
  char* wsb = (char*)d_ws;
  // workspace layout (requires ~492.3 MB):
  unsigned short* gx  = (unsigned short*)(wsb);                   // 393,216,000 B
  unsigned short* x   = (unsigned short*)(wsb + 393216000LL);     //  98,304,000 B
  unsigned short* wiT = (unsigned short*)(wsb + 491520000LL);     //     294,912 B
  unsigned short* whF = (unsigned short*)(wsb + 491814912LL);     //     393,216 B
  k_prep <<<1344, 256, 0, stream>>>(wi, wh, wiT, whF);
  k_embed<<<1000, 256, 0, stream>>>(states, actions, rewards, Ws, bs, Wa, ba, Wr, br, x);
  k_gx   <<<4000, 512, 0, stream>>>(x, wiT, bg, gx);
  k_gru  <<<16, 512, 0, stream>>>(gx, whF, (float*)d_out);
}

// Round 20
// 2183.564 us; speedup vs baseline: 2.4939x; 1.0011x over previous
//
#include <hip/hip_runtime.h>
#include <hip/hip_bf16.h>

#define TT   1000
#define BB   256
#define HID  256
#define GD   768
#define XD   192
#define NROW (TT*BB)

typedef __attribute__((ext_vector_type(8))) _Float16 half8;
typedef __attribute__((ext_vector_type(4))) float    float4_t;
typedef __attribute__((ext_vector_type(2))) unsigned uint2_t;

#define MFMA16(A,B,C) __builtin_amdgcn_mfma_f32_16x16x32_f16((A),(B),(C),0,0,0)

__device__ __forceinline__ void gll16(const void* g, void* l) {
  __builtin_amdgcn_global_load_lds((const __attribute__((address_space(1))) void*)g,
                                   (__attribute__((address_space(3))) void*)l, 16, 0, 0);
}

__device__ __forceinline__ unsigned short f2h(float f) {
  _Float16 h = (_Float16)f;                       // RTN-even
  union { _Float16 h; unsigned short u; } c; c.h = h; return c.u;
}
__device__ __forceinline__ uint2_t pk4h(float4_t v) {
  union { _Float16 h[4]; uint2_t u; } c;
  c.h[0] = (_Float16)v.x; c.h[1] = (_Float16)v.y;
  c.h[2] = (_Float16)v.z; c.h[3] = (_Float16)v.w;
  return c.u;
}
__device__ __forceinline__ float4_t h4_to_f4(uint2_t v) {
  union { uint2_t u; _Float16 h[4]; } c; c.u = v;
  float4_t f;
  f.x = (float)c.h[0]; f.y = (float)c.h[1];
  f.z = (float)c.h[2]; f.w = (float)c.h[3];
  return f;
}
__device__ __forceinline__ float sigx(float x) {
  return __builtin_amdgcn_rcpf(1.0f + __builtin_amdgcn_exp2f(-1.4426950408889634f * x));
}
__device__ __forceinline__ float tanhx(float x) {
  return 1.0f - 2.0f * __builtin_amdgcn_rcpf(1.0f + __builtin_amdgcn_exp2f(2.8853900817779268f * x));
}
__device__ __forceinline__ float4_t sig4(float4_t v){ float4_t o; o.x=sigx(v.x); o.y=sigx(v.y); o.z=sigx(v.z); o.w=sigx(v.w); return o; }
__device__ __forceinline__ float4_t tanh4(float4_t v){ float4_t o; o.x=tanhx(v.x); o.y=tanhx(v.y); o.z=tanhx(v.z); o.w=tanhx(v.w); return o; }
__device__ __forceinline__ float gelu1(float v){
  // jax.nn.gelu default = tanh approximation
  float c = v + 0.044715f * v * v * v;
  float e = __builtin_amdgcn_exp2f((0.7978845608028654f * 2.8853900817779268f) * c);
  float th = 1.0f - 2.0f * __builtin_amdgcn_rcpf(1.0f + e);
  return 0.5f * v * (1.0f + th);
}

// ---------------- prep: wiT[n][k] fp16, whF pre-fragmented fp16 ----------------
__global__ void k_prep(const float* __restrict__ wi, const float* __restrict__ wh,
                       unsigned short* __restrict__ wiT, unsigned short* __restrict__ whF)
{
  int tid = blockIdx.x * 256 + threadIdx.x;
  if (tid < GD*XD) {
    int n = tid / XD, k = tid - n*XD;
    wiT[tid] = f2h(wi[(size_t)k*GD + n]);
  }
  int t2 = tid - GD*XD;
  if (t2 >= 0 && t2 < 48*8*64*8) {
    int j = t2 & 7, l = (t2 >> 3) & 63, f = t2 >> 9;
    int mf = f >> 3, kf = f & 7;
    int k = kf*32 + ((l >> 4) << 3) + j;   // A-frag: lane row=l&15 (=ocol), k=(l>>4)*8+j
    int n = (mf << 4) + (l & 15);
    whF[t2] = f2h(wh[(size_t)k*GD + n]);
  }
}

// ---------------- embeddings -> x fp16 [NROW][192] ----------------
__global__ void k_embed(const float* __restrict__ st, const float* __restrict__ ac,
                        const float* __restrict__ rw,
                        const float* __restrict__ Ws, const float* __restrict__ bs,
                        const float* __restrict__ Wa, const float* __restrict__ ba,
                        const float* __restrict__ Wr, const float* __restrict__ br,
                        unsigned short* __restrict__ x)
{
  int lane = threadIdx.x & 63;
  int wid = blockIdx.x * (blockDim.x >> 6) + (threadIdx.x >> 6);
  int nw  = gridDim.x * (blockDim.x >> 6);
  float wsr[64], war[8];
  #pragma unroll
  for (int k = 0; k < 64; ++k) wsr[k] = Ws[k*64 + lane];   // lane j holds Ws[:,j]
  #pragma unroll
  for (int k = 0; k < 8; ++k) war[k] = Wa[k*64 + lane];
  float wrr = Wr[lane];
  float bsv = bs[lane], bav = ba[lane], brv = br[lane];
  for (int row = wid; row < NROW; row += nw) {
    const float4_t* sp = (const float4_t*)(st + (size_t)row*64);
    float a0 = bsv;
    #pragma unroll
    for (int q = 0; q < 16; ++q) {
      float4_t v = sp[q];
      a0 = fmaf(v.x, wsr[4*q+0], a0);
      a0 = fmaf(v.y, wsr[4*q+1], a0);
      a0 = fmaf(v.z, wsr[4*q+2], a0);
      a0 = fmaf(v.w, wsr[4*q+3], a0);
    }
    const float4_t* ap = (const float4_t*)(ac + (size_t)row*8);
    float a1 = bav;
    #pragma unroll
    for (int q = 0; q < 2; ++q) {
      float4_t v = ap[q];
      a1 = fmaf(v.x, war[4*q+0], a1);
      a1 = fmaf(v.y, war[4*q+1], a1);
      a1 = fmaf(v.z, war[4*q+2], a1);
      a1 = fmaf(v.w, war[4*q+3], a1);
    }
    float a2 = fmaf(rw[row], wrr, brv);
    unsigned short* xr = x + (size_t)row*XD;
    xr[lane]       = f2h(gelu1(a0));
    xr[64 + lane]  = f2h(gelu1(a1));
    xr[128 + lane] = f2h(gelu1(a2));
  }
}

// ---------------- gx = x @ wi + bg (fp16), FRAGMENT-LINEAR output ----------------
// Fragment (block, c, nf) -> contiguous 512 B chunk at
// ((block*48 + c)*4 + nf)*512 + lane*8.  Store = 64 lanes x 8 B contiguous.
__global__ __launch_bounds__(512, 2) void k_gx(const unsigned short* __restrict__ x,
                                               const unsigned short* __restrict__ wiT,
                                               const float* __restrict__ bg,
                                               unsigned short* __restrict__ gx)
{
  __shared__ half8 Xs[24*64];   // 24 B-frags (nf*6+kf), lane-linear
  __shared__ half8 As[16*64];   // 16 A-frags per stage phase
  int lane = threadIdx.x & 63;
  int wv   = threadIdx.x >> 6;
  int b    = lane & 15;
  int g8   = (lane >> 4) << 3;
  int row0 = blockIdx.x * 64;
  #pragma unroll
  for (int i = 0; i < 3; ++i) {
    int c = wv*3 + i, nf = c / 6, kf = c - nf*6;
    gll16(x + (size_t)(row0 + nf*16 + b)*XD + kf*32 + g8, &Xs[c*64]);
  }
  int g4 = g8 >> 1;
  float4_t acc[6][4];
  #pragma unroll
  for (int i = 0; i < 6; ++i) {
    float4_t bgv = *(const float4_t*)(bg + (wv + 8*i)*16 + g4);
    #pragma unroll
    for (int nf = 0; nf < 4; ++nf) acc[i][nf] = bgv;   // bias folded into C-init
  }
  half8 xb[4];
  for (int kf = 0; kf < 6; ++kf) {
    #pragma unroll
    for (int p = 0; p < 3; ++p) {
      __syncthreads();                      // prev phase's reads done
      #pragma unroll
      for (int i2 = 0; i2 < 2; ++i2) {
        int q = wv*2 + i2;
        gll16(wiT + (size_t)((p*16 + q)*16 + b)*XD + kf*32 + g8, &As[q*64]);
      }
      __syncthreads();                      // stage complete (drains vmcnt)
      if (p == 0) {
        #pragma unroll
        for (int nf = 0; nf < 4; ++nf) xb[nf] = Xs[(nf*6 + kf)*64 + lane];
      }
      half8 af0 = As[wv*64 + lane];
      half8 af1 = As[(wv+8)*64 + lane];
      #pragma unroll
      for (int nf = 0; nf < 4; ++nf) {
        acc[2*p  ][nf] = MFMA16(af0, xb[nf], acc[2*p  ][nf]);
        acc[2*p+1][nf] = MFMA16(af1, xb[nf], acc[2*p+1][nf]);
      }
    }
  }
  char* gxc = (char*)gx;
  #pragma unroll
  for (int i = 0; i < 6; ++i) {
    #pragma unroll
    for (int nf = 0; nf < 4; ++nf) {
      size_t idx = (((size_t)blockIdx.x*48 + (wv + 8*i))*4 + nf)*512 + lane*8;
      *(uint2_t*)(gxc + idx) = pk4h(acc[i][nf]);
    }
  }
}

// ---------------- GRU recurrence (r12, empirical optimum of this design space) ----------------
// 8 waves, builtin MFMA, ~124 resident regs + compiler-pipelined L2 weight
// stream. Manual alternatives (AGPR pinning r13-r19) all lost more to
// serialization or hazards than the stream costs. Frag-linear slab + 528B-padded h/rh.
__global__
__attribute__((amdgpu_flat_work_group_size(512, 512), amdgpu_waves_per_eu(2, 2)))
void k_gru(const unsigned short* __restrict__ gx,
           const unsigned short* __restrict__ whF,
           float* __restrict__ out)
{
  __shared__ char smem[98304];     // STATIC (1 WG/CU): h 8448 + rh 8448 + 2x24576 slabs
  char* h_lds  = smem;             // [16][264] fp16: row stride 528 B
  char* rh_lds = smem + 8448;
  char* gxb    = smem + 16896;     // 2 x 24576 B frag-linear slab
  const int tid  = threadIdx.x;
  const int lane = tid & 63;
  const int wv   = tid >> 6;
  const int wg   = blockIdx.x;
  const int b    = lane & 15;
  const int g    = lane >> 4;
  const int kr4  = g << 2;

  // wave wv owns ocols [wv*32, wv*32+32) of z, r and a. 48 frags = 192 regs.
  half8 wz0[8], wz1[8], wr0[8], wr1[8], wa0[8], wa1[8];
  #pragma unroll
  for (int kf = 0; kf < 8; ++kf) {
    wz0[kf] = *(const half8*)(whF + ((size_t)((( 2*wv    )*8 + kf)*64 + lane) << 3));
    wz1[kf] = *(const half8*)(whF + ((size_t)((( 2*wv + 1)*8 + kf)*64 + lane) << 3));
    wr0[kf] = *(const half8*)(whF + ((size_t)(((16 + 2*wv)*8 + kf)*64 + lane) << 3));
    wr1[kf] = *(const half8*)(whF + ((size_t)(((17 + 2*wv)*8 + kf)*64 + lane) << 3));
    wa0[kf] = *(const half8*)(whF + ((size_t)(((32 + 2*wv)*8 + kf)*64 + lane) << 3));
    wa1[kf] = *(const half8*)(whF + ((size_t)(((33 + 2*wv)*8 + kf)*64 + lane) << 3));
  }
  #pragma unroll
  for (int kf = 0; kf < 8; ++kf) {
    asm volatile("" : "+v"(wz0[kf]));
    asm volatile("" : "+v"(wz1[kf]));
    asm volatile("" : "+v"(wr0[kf]));
    asm volatile("" : "+v"(wr1[kf]));
    asm volatile("" : "+v"(wa0[kf]));
    asm volatile("" : "+v"(wa1[kf]));
  }
  for (int i = tid; i < 2112; i += 512) ((unsigned*)h_lds)[i] = 0u;   // h0 = 0 (8448 B)

  // slab staging: frag-linear. Dest byte D = i*8192 + tid*16 (wave-uniform base
  // + lane*16). Source within the (bt,nf) block: c = D/512, r = D%512 ->
  // soff = nf*512 + c*2048 + r.
  const int nf   = wg & 3;
  const int bsel = wg >> 2;
  int soff[3], dch[3];
  #pragma unroll
  for (int i = 0; i < 3; ++i) {
    int c = i*16 + (tid >> 5);
    int r = (tid & 31) << 4;
    soff[i] = nf*512 + c*2048 + r;
    dch[i]  = i*8192 + tid*16;
  }
  const char* gxc = (const char*)gx;
  #pragma unroll
  for (int i = 0; i < 3; ++i)
    gll16(gxc + (size_t)bsel*98304 + soff[i], gxb + dch[i]);
  __syncthreads();   // full drain: t=0 slab ready, h zeroed

  float4_t hf0 = {0.f, 0.f, 0.f, 0.f}, hf1 = hf0;   // fp32 h for owned cols
  const char* hb_base = h_lds + b*528;
  const char* rb_base = rh_lds + b*528;
  const int off_h0 = (wv*32 + kr4) << 1;        // h/rh row-internal byte offset
  const int off_h1 = off_h0 + 32;
  const int lz0 = ( 2*wv    )*512 + lane*8;     // slab frag offsets (C-init)
  const int lz1 = ( 2*wv + 1)*512 + lane*8;
  const int lr0 = (16 + 2*wv)*512 + lane*8;
  const int lr1 = (17 + 2*wv)*512 + lane*8;
  const int la0 = (32 + 2*wv)*512 + lane*8;
  const int la1 = (33 + 2*wv)*512 + lane*8;

  for (int t = 0; t < TT; ++t) {
    // TOP barrier: counted vmcnt(2) -> 3 glls done, 2 hs-stores may stay in flight
    asm volatile("s_waitcnt vmcnt(2) lgkmcnt(0)" ::: "memory");
    __builtin_amdgcn_s_barrier();
    asm volatile("" ::: "memory");   // no memory op hoists above the barrier
    if (t + 1 < TT) {   // prefetch next slab; stays in flight across mid barrier
      const char* slab = gxc + ((size_t)(t+1)*4 + bsel)*98304;
      char* dstb = gxb + 24576*((t+1) & 1);
      #pragma unroll
      for (int i = 0; i < 3; ++i) gll16(slab + soff[i], dstb + dch[i]);
    }
    const char* cur = gxb + 24576*(t & 1);
    // ---- phase 1: zr^T = sigmoid(gx_zr + wh_zr^T @ h^T) ----
    float4_t az0 = h4_to_f4(*(const uint2_t*)(cur + lz0));
    float4_t az1 = h4_to_f4(*(const uint2_t*)(cur + lz1));
    float4_t ar0 = h4_to_f4(*(const uint2_t*)(cur + lr0));
    float4_t ar1 = h4_to_f4(*(const uint2_t*)(cur + lr1));
    #pragma unroll
    for (int kf = 0; kf < 8; ++kf) {
      half8 hb = *(const half8*)(hb_base + kf*64 + (g << 4));
      az0 = MFMA16(wz0[kf], hb, az0);
      az1 = MFMA16(wz1[kf], hb, az1);
      ar0 = MFMA16(wr0[kf], hb, ar0);
      ar1 = MFMA16(wr1[kf], hb, ar1);
    }
    float4_t z0 = sig4(az0), z1 = sig4(az1);
    float4_t rh0 = sig4(ar0) * hf0, rh1 = sig4(ar1) * hf1;   // r*h, all in-lane
    *(uint2_t*)(rh_lds + b*528 + off_h0) = pk4h(rh0);
    *(uint2_t*)(rh_lds + b*528 + off_h1) = pk4h(rh1);
    // MID barrier: LDS-only wait, prefetch glls stay outstanding
    asm volatile("s_waitcnt lgkmcnt(0)" ::: "memory");
    __builtin_amdgcn_s_barrier();
    asm volatile("" ::: "memory");
    // ---- phase 2: a^T = tanh(gx_a + wh_a^T @ (r*h)^T) ----
    float4_t aa0 = h4_to_f4(*(const uint2_t*)(cur + la0));
    float4_t aa1 = h4_to_f4(*(const uint2_t*)(cur + la1));
    #pragma unroll
    for (int kf = 0; kf < 8; ++kf) {
      half8 rb = *(const half8*)(rb_base + kf*64 + (g << 4));
      aa0 = MFMA16(wa0[kf], rb, aa0);
      aa1 = MFMA16(wa1[kf], rb, aa1);
    }
    float4_t a0 = tanh4(aa0), a1 = tanh4(aa1);
    float4_t hn0 = hf0 + z0 * (a0 - hf0);   // (1-z)h + z*a
    float4_t hn1 = hf1 + z1 * (a1 - hf1);
    hf0 = hn0; hf1 = hn1;
    *(uint2_t*)(h_lds + b*528 + off_h0) = pk4h(hn0);
    *(uint2_t*)(h_lds + b*528 + off_h1) = pk4h(hn1);
    float* op = out + (((size_t)t*BB + wg*16 + b) << 8) + wv*32 + kr4;
    *(float4_t*)op = hn0;
    *(float4_t*)(op + 16) = hn1;
  }
}

extern "C" void kernel_launch(void* const* d_in, const int* in_sizes, int n_in,
                              void* d_out, int out_size, void* d_ws, size_t ws_size,
                              hipStream_t stream) {
  (void)in_sizes; (void)n_in; (void)out_size; (void)ws_size;
  const float* states  = (const float*)d_in[0];
  const float* actions = (const float*)d_in[1];
  const float* rewards = (const float*)d_in[2];
  const float* Ws = (const float*)d_in[3];
  const float* bs = (const float*)d_in[4];
  const float* Wa = (const float*)d_in[5];
  const float* ba = (const float*)d_in[6];
  const float* Wr = (const float*)d_in[7];
  const float* br = (const float*)d_in[8];
  const float* wi = (const float*)d_in[9];
  const float* wh = (const float*)d_in[10];
  const float* bg = (const float*)d_in[11];
  char* wsb = (char*)d_ws;
  // workspace layout (requires ~492.3 MB):
  unsigned short* gx  = (unsigned short*)(wsb);                   // 393,216,000 B
  unsigned short* x   = (unsigned short*)(wsb + 393216000LL);     //  98,304,000 B
  unsigned short* wiT = (unsigned short*)(wsb + 491520000LL);     //     294,912 B
  unsigned short* whF = (unsigned short*)(wsb + 491814912LL);     //     393,216 B
  k_prep <<<1344, 256, 0, stream>>>(wi, wh, wiT, whF);
  k_embed<<<1000, 256, 0, stream>>>(states, actions, rewards, Ws, bs, Wa, ba, Wr, br, x);
  k_gx   <<<4000, 512, 0, stream>>>(x, wiT, bg, gx);
  k_gru  <<<16, 512, 0, stream>>>(gx, whF, (float*)d_out);
}